// Round 10
// baseline (1635.682 us; speedup 1.0000x reference)
//
#include <hip/hip_runtime.h>
#include <hip/hip_bf16.h>
#include <math.h>

#define B_ 128
#define T_ 128
#define D_ 512
#define STEPS_ 255

#define REF_COMP 4096
#define REF_ZERO 8192

using short8   = __attribute__((ext_vector_type(8))) short;
using ushort8  = __attribute__((ext_vector_type(8))) unsigned short;
using ushort4v = __attribute__((ext_vector_type(4))) unsigned short;
using float4v  = __attribute__((ext_vector_type(4))) float;

__device__ __forceinline__ unsigned short rne_bf16(float f){
  union { float f; unsigned u; } v; v.f = f;
  unsigned u = v.u;
  u += 0x7FFFu + ((u >> 16) & 1u);
  return (unsigned short)(u >> 16);
}
__device__ __forceinline__ float bf2f(unsigned short u){
  union { unsigned u; float f; } x; x.u = ((unsigned)u) << 16; return x.f;
}
__device__ __forceinline__ float fast_tanh(float x){
  float xc = fminf(9.0f, fmaxf(-9.0f, x));
  float e  = __expf(2.0f * xc);
  return (e - 1.0f) * __builtin_amdgcn_rcpf(e + 1.0f);
}
// parity grouping: group-slot j -> batch row (evens first, then odds)
__device__ __forceinline__ int rowB(int j){ return (j < 64) ? (2*j) : (2*(j-64)+1); }

// 8 x 16B coherent (LLC) loads of a 512B c-half's A-fragments, 1 round-trip.
__device__ __forceinline__ void load_c8(const char* p, short8* a){
  asm volatile(
    "global_load_dwordx4 %0, %8, off sc0 sc1\n\t"
    "global_load_dwordx4 %1, %8, off offset:64 sc0 sc1\n\t"
    "global_load_dwordx4 %2, %8, off offset:128 sc0 sc1\n\t"
    "global_load_dwordx4 %3, %8, off offset:192 sc0 sc1\n\t"
    "global_load_dwordx4 %4, %8, off offset:256 sc0 sc1\n\t"
    "global_load_dwordx4 %5, %8, off offset:320 sc0 sc1\n\t"
    "global_load_dwordx4 %6, %8, off offset:384 sc0 sc1\n\t"
    "global_load_dwordx4 %7, %8, off offset:448 sc0 sc1\n\t"
    "s_waitcnt vmcnt(0)"
    : "=&v"(a[0]), "=&v"(a[1]), "=&v"(a[2]), "=&v"(a[3]),
      "=&v"(a[4]), "=&v"(a[5]), "=&v"(a[6]), "=&v"(a[7])
    : "v"(p)
    : "memory");
}

__device__ __forceinline__ void cstore_cc(unsigned short* p, unsigned v){
  asm volatile("global_store_short %0, %1, off sc0 sc1" :: "v"(p), "v"(v) : "memory");
}

// ---------------- zero init: flags / bitmaps / zero page ---------------------
__global__ void k_zero(int* __restrict__ flags, int* __restrict__ anyLR,
                       int* __restrict__ gIter, unsigned short* __restrict__ zeroPg){
  int t = threadIdx.x;
  for (int i = t; i < 2048; i += 256) flags[i] = 0;
  for (int i = t; i < 1024; i += 256) anyLR[i] = 0;
  if (t < 16) gIter[t] = 0;
  for (int i = t; i < 1024; i += 256) zeroPg[i] = 0;
}

// ---------------- pre-pass: symbolic stack simulation (1 block / row) --------
// ref encoding: 0..127 = BUF idx; 4096+k = COMP k; 8192 = initial zero; -1 = none
__global__ __launch_bounds__(64) void k_prepass2(
    const int* __restrict__ tr,
    short* __restrict__ redL, short* __restrict__ redR,
    short* __restrict__ uL, short* __restrict__ uR,
    short* __restrict__ cL, short* __restrict__ cR,
    int* __restrict__ nred, int* __restrict__ encRef,
    int* __restrict__ gIter, int* __restrict__ anyLR){
  __shared__ int trs[STEPS_];
  int b = blockIdx.x, lane = threadIdx.x;
  for (int i = lane; i < STEPS_; i += 64) trs[i] = tr[b*STEPS_ + i];
  __syncthreads();
  if (lane != 0) return;
  short stk[T_ + 2];
  stk[0] = (short)REF_ZERO; stk[1] = (short)REF_ZERO;
  int ptr = 2, bptr = 0, k = 0;
  int g = (b & 1) ? 4 + ((b >> 1) >> 4) : ((b >> 1) >> 4);
  for (int t = 0; t < STEPS_; t++){
    int tt = trs[t];
    int rl = -1, rr = -1;
    if (tt == 0){                      // SHIFT
      int j = bptr; if (j > T_-1) j = T_-1;
      int wi = ptr; if (wi < 0) wi = 0; if (wi > T_+1) wi = T_+1;
      stk[wi] = (short)j;
      ptr++; bptr++;
    } else if (tt == 1){               // REDUCE
      int i1 = ptr-1; if (i1 < 0) i1 = 0; if (i1 > T_+1) i1 = T_+1;
      int i2 = ptr-2; if (i2 < 0) i2 = 0; if (i2 > T_+1) i2 = T_+1;
      rr = stk[i1]; rl = stk[i2];
      short sL = (rl >= 0 && rl < REF_COMP) ? (short)rl : (short)-1;   // static buf
      short sR = (rr >= 0 && rr < REF_COMP) ? (short)rr : (short)-1;
      short dL = (rl >= REF_COMP && rl < REF_ZERO) ? (short)(rl - REF_COMP) : (short)-1; // dyn comp
      short dR = (rr >= REF_COMP && rr < REF_ZERO) ? (short)(rr - REF_COMP) : (short)-1;
      uL[b*128 + k] = sL; uR[b*128 + k] = sR;
      cL[b*128 + k] = dL; cR[b*128 + k] = dR;
      int bits = (dL >= 0 ? 1 : 0) | (dR >= 0 ? 2 : 0);
      if (bits) atomicOr(anyLR + g*128 + k, bits);
      int wi = ptr-2; if (wi < 0) wi = 0; if (wi > T_+1) wi = T_+1;
      stk[wi] = (short)(REF_COMP + k);
      k++; ptr--;
    }                                  // SKIP: no change
    redL[b*STEPS_ + t] = (short)rl;
    redR[b*STEPS_ + t] = (short)rr;
  }
  for (int kk = k; kk < 128; kk++){
    uL[b*128+kk] = -1; uR[b*128+kk] = -1; cL[b*128+kk] = -1; cR[b*128+kk] = -1;
  }
  int ei = ptr-1; if (ei < 0) ei = 0; if (ei > T_+1) ei = T_+1;
  encRef[b] = stk[ei];
  nred[b] = k;
  atomicMax(gIter + g, k);
}

// ---------------- W prep: fp32 [1024][512] -> bf16 MFMA-B-fragment-linear ----
__global__ void k_wprep(const float* __restrict__ W, unsigned short* __restrict__ Wo){
  int t = blockIdx.x*256 + threadIdx.x;           // t < 524288
  int e  = t & 7;
  int l  = (t >> 3) & 63;
  int kt = (t >> 9) & 31;
  int nt = (t >> 14);
  int krow = kt*32 + (l >> 4)*8 + e;
  int ncol = nt*16 + (l & 15);
  Wo[t] = rne_bf16(W[krow*512 + ncol]);
}

// ---------------- U GEMM: U[(b,k)][col] = W_L*leftStatic + W_R*rightStatic + b
__global__ __launch_bounds__(256) void k_ugemm(
    const float* __restrict__ bufs, const float* __restrict__ bias,
    const unsigned short* __restrict__ Wo,
    const short* __restrict__ uL, const short* __restrict__ uR,
    const float* __restrict__ zeroF, unsigned short* __restrict__ U){
  int mt = blockIdx.x & 255, ntB = blockIdx.x >> 8;
  int w = threadIdx.x >> 6, lane = threadIdx.x & 63;
  int rbase = mt*64 + w*16;
  int arow = rbase + (lane & 15);
  int b = arow >> 7;
  int refL = (int)uL[arow], refR = (int)uR[arow];
  const float* pL = (refL >= 0) ? (bufs + ((size_t)b*T_ + refL)*D_) : zeroF;
  const float* pR = (refR >= 0) ? (bufs + ((size_t)b*T_ + refR)*D_) : zeroF;
  int eoff = (lane >> 4) * 8;
  float4v acc[8];
  #pragma unroll
  for (int nt = 0; nt < 8; ++nt) acc[nt] = (float4v){0.f,0.f,0.f,0.f};
  for (int kt = 0; kt < 32; ++kt){
    const float* src = (kt < 16) ? pL : pR;
    int off = (kt & 15)*32 + eoff;
    float4v f0 = *reinterpret_cast<const float4v*>(src + off);
    float4v f1 = *reinterpret_cast<const float4v*>(src + off + 4);
    short8 a;
    a[0]=(short)rne_bf16(f0[0]); a[1]=(short)rne_bf16(f0[1]);
    a[2]=(short)rne_bf16(f0[2]); a[3]=(short)rne_bf16(f0[3]);
    a[4]=(short)rne_bf16(f1[0]); a[5]=(short)rne_bf16(f1[1]);
    a[6]=(short)rne_bf16(f1[2]); a[7]=(short)rne_bf16(f1[3]);
    #pragma unroll
    for (int nt = 0; nt < 8; ++nt){
      const short8* bp = reinterpret_cast<const short8*>(Wo)
                         + (((size_t)(ntB*8 + nt)*32 + kt)*64 + lane);
      acc[nt] = __builtin_amdgcn_mfma_f32_16x16x32_bf16(a, *bp, acc[nt], 0, 0, 0);
    }
  }
  #pragma unroll
  for (int nt = 0; nt < 8; ++nt){
    int col = ntB*128 + nt*16 + (lane & 15);
    float bc = bias[col];
    #pragma unroll
    for (int j = 0; j < 4; ++j){
      int orow = rbase + (lane >> 4)*4 + j;
      U[(size_t)orow*512 + col] = rne_bf16(acc[nt][j] + bc);
    }
  }
}

// ---------------- chain: 8 groups x 2 WGs (256-col half), W_L in VGPRs -------
// Per WG: 8 waves x 2 ntiles; W_L half = 128 B-frag VGPRs/wave (no W traffic).
// Phase1: own K-half from LDS c-buffer (intra-WG only). Phase2: partner's 8KB
// half after ONE flag poll + one sc0sc1 vector load. U added post-MFMA.
__global__ __launch_bounds__(512, 2) void k_chain8(
    const unsigned short* __restrict__ Wo, const unsigned short* __restrict__ U,
    const short* __restrict__ cL, const short* __restrict__ cR,
    const int* __restrict__ nred, const int* __restrict__ gIter,
    const int* __restrict__ anyLR, const unsigned short* __restrict__ zeroPg,
    unsigned short* __restrict__ CompBf, int* __restrict__ flags){
  __shared__ unsigned short cbuf[2][4096];        // [k-parity][16 rows x 256 cols]
  const int tid = threadIdx.x, lane = tid & 63, w = tid >> 6;
  const int g = blockIdx.x >> 1, h = blockIdx.x & 1;
  const int colLane = lane & 15, rq = lane >> 4;

  // W_L B-fragments resident in VGPRs: ntg = h*16 + w*2 + t, kt 0..15 (K 0..511)
  short8 Wreg0[16], Wreg1[16];
  #pragma unroll
  for (int kt = 0; kt < 16; ++kt){
    Wreg0[kt] = *(reinterpret_cast<const short8*>(Wo) +
                  (((size_t)(h*16 + w*2 + 0)*32 + kt)*64 + lane));
    Wreg1[kt] = *(reinterpret_cast<const short8*>(Wo) +
                  (((size_t)(h*16 + w*2 + 1)*32 + kt)*64 + lane));
  }

  const int myb = rowB(g*16 + colLane);
  const int myNred = nred[myb];
  const int iters = gIter[g];
  int bS[4];
  #pragma unroll
  for (int j = 0; j < 4; ++j) bS[j] = rowB(g*16 + rq*4 + j);
  const int col0 = (h*16 + w*2)*16 + colLane;     // global col of t=0
  size_t Ub[4];
  #pragma unroll
  for (int j = 0; j < 4; ++j) Ub[j] = (size_t)bS[j]*65536 + col0;

  int* pflag = flags + ((g*2 + (h^1)) << 4);      // partner's flag
  int* mflag = flags + ((g*2 + h) << 4);          // mine

  for (int k = 0; k < iters; ++k){
    const int afl = anyLR[g*128 + k];
    // U prefetch — consumed only at tanh, so HBM latency hides under phases
    unsigned short uv0[4], uv1[4];
    #pragma unroll
    for (int j = 0; j < 4; ++j){
      uv0[j] = U[Ub[j] + (size_t)k*512];
      uv1[j] = U[Ub[j] + (size_t)k*512 + 16];
    }
    float4v accA0 = {0.f,0.f,0.f,0.f}, accA1 = {0.f,0.f,0.f,0.f};
    float4v accB0 = {0.f,0.f,0.f,0.f}, accB1 = {0.f,0.f,0.f,0.f};

    if (afl != 0){
      int rl = (k < myNred) ? (int)cL[myb*128 + k] : -1;
      if (afl & 1){
        // ---- phase 1: own K-half (no cross-WG dependency) ----
        bool ownLds = (k > 0) && __all((rl == k-1) || (rl < 0));
        short8 aO[8];
        if (ownLds){
          const char* cb = (const char*)cbuf[(k-1) & 1];
          int base = colLane*512 + rq*16;
          #pragma unroll
          for (int kt = 0; kt < 8; ++kt){
            int ad = (base + kt*64) ^ ((colLane & 7) << 4);
            aO[kt] = *reinterpret_cast<const short8*>(cb + ad);
          }
        } else {
          const char* p = (rl >= 0)
            ? (const char*)(CompBf + ((size_t)myb*128 + rl)*512 + h*256)
            : (const char*)zeroPg;
          load_c8(p + rq*16, aO);
        }
        if (rl < 0){
          #pragma unroll
          for (int kt = 0; kt < 8; ++kt) aO[kt] = (short8)0;
        }
        #pragma unroll
        for (int kt = 0; kt < 8; ++kt){
          accA0 = __builtin_amdgcn_mfma_f32_16x16x32_bf16(aO[kt], Wreg0[h*8 + kt], accA0, 0, 0, 0);
          accA1 = __builtin_amdgcn_mfma_f32_16x16x32_bf16(aO[kt], Wreg1[h*8 + kt], accA1, 0, 0, 0);
        }
      }
      // ---- sync: partner's step k-1 must be complete ----
      if (k > 0){
        int guard = 0;
        for (;;){
          int fv = __hip_atomic_load(pflag, __ATOMIC_RELAXED, __HIP_MEMORY_SCOPE_AGENT);
          if (fv >= k) break;
          __builtin_amdgcn_s_sleep(1);
          if (++guard > (1 << 26)) break;         // safety: never hang
        }
        asm volatile("" ::: "memory");            // compiler ordering only
      }
      if (afl & 1){
        // ---- phase 2: partner K-half via LLC ----
        short8 aP[8];
        const char* p = (rl >= 0)
          ? (const char*)(CompBf + ((size_t)myb*128 + rl)*512 + (h^1)*256)
          : (const char*)zeroPg;
        load_c8(p + rq*16, aP);
        if (rl < 0){
          #pragma unroll
          for (int kt = 0; kt < 8; ++kt) aP[kt] = (short8)0;
        }
        #pragma unroll
        for (int kt = 0; kt < 8; ++kt){
          accB0 = __builtin_amdgcn_mfma_f32_16x16x32_bf16(aP[kt], Wreg0[(h^1)*8 + kt], accB0, 0, 0, 0);
          accB1 = __builtin_amdgcn_mfma_f32_16x16x32_bf16(aP[kt], Wreg1[(h^1)*8 + kt], accB1, 0, 0, 0);
        }
      }
      if (afl & 2){
        // ---- general fallback: dynamic right; W_R frags from global Wo ----
        int rr = (k < myNred) ? (int)cR[myb*128 + k] : -1;
        const char* p = (rr >= 0)
          ? (const char*)(CompBf + ((size_t)myb*128 + rr)*512)
          : (const char*)zeroPg;
        #pragma unroll
        for (int half = 0; half < 2; ++half){
          short8 aR[8];
          load_c8(p + half*512 + rq*16, aR);
          if (rr < 0){
            #pragma unroll
            for (int kt = 0; kt < 8; ++kt) aR[kt] = (short8)0;
          }
          #pragma unroll
          for (int kt = 0; kt < 8; ++kt){
            const short8* bp0 = reinterpret_cast<const short8*>(Wo)
              + (((size_t)(h*16 + w*2 + 0)*32 + 16 + half*8 + kt)*64 + lane);
            const short8* bp1 = reinterpret_cast<const short8*>(Wo)
              + (((size_t)(h*16 + w*2 + 1)*32 + 16 + half*8 + kt)*64 + lane);
            accB0 = __builtin_amdgcn_mfma_f32_16x16x32_bf16(aR[kt], *bp0, accB0, 0, 0, 0);
            accB1 = __builtin_amdgcn_mfma_f32_16x16x32_bf16(aR[kt], *bp1, accB1, 0, 0, 0);
          }
        }
      }
    }
    // ---- finish: tanh(U + acc), scatter to CompBf (sc0sc1) + own LDS half ----
    char* cw = (char*)cbuf[k & 1];
    #pragma unroll
    for (int j = 0; j < 4; ++j){
      float v0 = fast_tanh(accA0[j] + accB0[j] + bf2f(uv0[j]));
      float v1 = fast_tanh(accA1[j] + accB1[j] + bf2f(uv1[j]));
      unsigned us0 = (unsigned)rne_bf16(v0);
      unsigned us1 = (unsigned)rne_bf16(v1);
      size_t rb = ((size_t)bS[j]*128 + k)*512;
      cstore_cc(CompBf + rb + col0, us0);
      cstore_cc(CompBf + rb + col0 + 16, us1);
      int rloc = rq*4 + j;
      int c0 = (w*2)*16 + colLane;                // local col of t=0
      int ad0 = (rloc*512 + c0*2) ^ ((rloc & 7) << 4);
      int ad1 = (rloc*512 + (c0 + 16)*2) ^ ((rloc & 7) << 4);
      *reinterpret_cast<unsigned short*>(cw + ad0) = (unsigned short)us0;
      *reinterpret_cast<unsigned short*>(cw + ad1) = (unsigned short)us1;
    }
    asm volatile("s_waitcnt vmcnt(0)" ::: "memory");  // my c-half at LLC
    __syncthreads();                                   // all waves drained + LDS done
    if (tid == 0)
      __hip_atomic_store(mflag, k + 1, __ATOMIC_RELAXED, __HIP_MEMORY_SCOPE_AGENT);
  }
}

// ---------------- output writer: pure copy/scatter, memory-bound ------------
__global__ __launch_bounds__(256) void k_out(
    const float* __restrict__ bufs, const unsigned short* __restrict__ CompBf,
    const short* __restrict__ redL, const short* __restrict__ redR,
    const int* __restrict__ encRef, float* __restrict__ out)
{
  int r = blockIdx.x*2 + (threadIdx.x >> 7);      // 65536 output rows of 512 f32
  int q = threadIdx.x & 127;                      // float4 index within row
  int ref, b;
  float* dst;
  if (r < B_){                                    // enc block
    b = r; ref = encRef[r];
    dst = out + (size_t)r*D_;
  } else {                                        // attended block
    int z = r - B_;
    b = z / 511; int s = z - b*511;
    dst = out + (size_t)B_*D_ + (size_t)z*D_;
    if (s == 510) ref = encRef[b];
    else { int t = s >> 1; ref = (s & 1) ? (int)redR[b*STEPS_ + t] : (int)redL[b*STEPS_ + t]; }
  }
  float4v v = {0.f, 0.f, 0.f, 0.f};
  if (ref >= 0 && ref < REF_COMP){
    v = reinterpret_cast<const float4v*>(bufs + ((size_t)b*T_ + ref)*D_)[q];
  } else if (ref >= REF_COMP && ref < REF_ZERO){
    ushort4v u = reinterpret_cast<const ushort4v*>(CompBf + ((size_t)b*128 + (ref - REF_COMP))*D_)[q];
    v[0] = bf2f(u[0]); v[1] = bf2f(u[1]); v[2] = bf2f(u[2]); v[3] = bf2f(u[3]);
  }
  reinterpret_cast<float4v*>(dst)[q] = v;
}

// ---------------- launch ----------------------------------------------------
extern "C" void kernel_launch(void* const* d_in, const int* in_sizes, int n_in,
                              void* d_out, int out_size, void* d_ws, size_t ws_size,
                              hipStream_t stream){
  const float* bufs = (const float*)d_in[0];
  const float* W    = (const float*)d_in[1];
  const float* bias = (const float*)d_in[2];
  const int*   tr   = (const int*)d_in[3];
  float* out = (float*)d_out;
  char* ws = (char*)d_ws;

  unsigned short* Wo     = (unsigned short*)(ws);               //  1,048,576
  unsigned short* CompBf = (unsigned short*)(ws + 1048576);     // 16,777,216
  unsigned short* U      = (unsigned short*)(ws + 17825792);    // 16,777,216
  short* redL   = (short*)(ws + 34603008);                      //     65,536
  short* redR   = (short*)(ws + 34668544);                      //     65,536
  short* uL     = (short*)(ws + 34734080);                      //     32,768
  short* uR     = (short*)(ws + 34766848);                      //     32,768
  short* cL     = (short*)(ws + 34799616);                      //     32,768
  short* cR     = (short*)(ws + 34832384);                      //     32,768
  int* nred     = (int*)(ws + 34865152);                        //        512
  int* encRef   = (int*)(ws + 34865664);                        //        512
  int* gIter    = (int*)(ws + 34866176);                        //        256
  int* flags    = (int*)(ws + 34866432);                        //      8,192
  int* anyLR    = (int*)(ws + 34874624);                        //      4,096
  unsigned short* zeroPg = (unsigned short*)(ws + 34878720);    //      2,048

  k_zero<<<1, 256, 0, stream>>>(flags, anyLR, gIter, zeroPg);
  k_prepass2<<<128, 64, 0, stream>>>(tr, redL, redR, uL, uR, cL, cR, nred, encRef, gIter, anyLR);
  k_wprep<<<2048, 256, 0, stream>>>(W, Wo);
  k_ugemm<<<1024, 256, 0, stream>>>(bufs, bias, Wo, uL, uR, (const float*)zeroPg, U);
  k_chain8<<<16, 512, 0, stream>>>(Wo, U, cL, cR, nred, gIter, anyLR, zeroPg, CompBf, flags);
  k_out<<<32768, 256, 0, stream>>>(bufs, CompBf, redL, redR, encRef, out);
}

// Round 11
// 958.891 us; speedup vs baseline: 1.7058x; 1.7058x over previous
//
#include <hip/hip_runtime.h>
#include <hip/hip_bf16.h>
#include <math.h>

#define B_ 128
#define T_ 128
#define D_ 512
#define STEPS_ 255

#define REF_COMP 4096
#define REF_ZERO 8192

using short8   = __attribute__((ext_vector_type(8))) short;
using ushort8  = __attribute__((ext_vector_type(8))) unsigned short;
using ushort4v = __attribute__((ext_vector_type(4))) unsigned short;
using float4v  = __attribute__((ext_vector_type(4))) float;

__device__ __forceinline__ unsigned short rne_bf16(float f){
  union { float f; unsigned u; } v; v.f = f;
  unsigned u = v.u;
  u += 0x7FFFu + ((u >> 16) & 1u);
  return (unsigned short)(u >> 16);
}
__device__ __forceinline__ float bf2f(unsigned short u){
  union { unsigned u; float f; } x; x.u = ((unsigned)u) << 16; return x.f;
}
__device__ __forceinline__ float fast_tanh(float x){
  float xc = fminf(9.0f, fmaxf(-9.0f, x));
  float e  = __expf(2.0f * xc);
  return (e - 1.0f) * __builtin_amdgcn_rcpf(e + 1.0f);
}
// parity grouping: group-slot j -> batch row (evens first, then odds)
__device__ __forceinline__ int rowB(int j){ return (j < 64) ? (2*j) : (2*(j-64)+1); }

// 8 x 16B coherent (LLC) loads of a 512B c-half's A-fragments, 1 round-trip.
__device__ __forceinline__ void load_c8(const char* p, short8* a){
  asm volatile(
    "global_load_dwordx4 %0, %8, off sc0 sc1\n\t"
    "global_load_dwordx4 %1, %8, off offset:64 sc0 sc1\n\t"
    "global_load_dwordx4 %2, %8, off offset:128 sc0 sc1\n\t"
    "global_load_dwordx4 %3, %8, off offset:192 sc0 sc1\n\t"
    "global_load_dwordx4 %4, %8, off offset:256 sc0 sc1\n\t"
    "global_load_dwordx4 %5, %8, off offset:320 sc0 sc1\n\t"
    "global_load_dwordx4 %6, %8, off offset:384 sc0 sc1\n\t"
    "global_load_dwordx4 %7, %8, off offset:448 sc0 sc1\n\t"
    "s_waitcnt vmcnt(0)"
    : "=&v"(a[0]), "=&v"(a[1]), "=&v"(a[2]), "=&v"(a[3]),
      "=&v"(a[4]), "=&v"(a[5]), "=&v"(a[6]), "=&v"(a[7])
    : "v"(p)
    : "memory");
}

__device__ __forceinline__ void cstore_cc(unsigned short* p, unsigned v){
  asm volatile("global_store_short %0, %1, off sc0 sc1" :: "v"(p), "v"(v) : "memory");
}

// ---------------- zero init: flags / bitmaps / zero page ---------------------
__global__ void k_zero(int* __restrict__ flags, int* __restrict__ anyLR,
                       int* __restrict__ gIter, unsigned short* __restrict__ zeroPg){
  int t = threadIdx.x;
  for (int i = t; i < 2048; i += 256) flags[i] = 0;
  for (int i = t; i < 1024; i += 256) anyLR[i] = 0;
  if (t < 16) gIter[t] = 0;
  for (int i = t; i < 1024; i += 256) zeroPg[i] = 0;
}

// ---------------- pre-pass: symbolic stack simulation (1 block / row) --------
// ref encoding: 0..127 = BUF idx; 4096+k = COMP k; 8192 = initial zero; -1 = none
__global__ __launch_bounds__(64) void k_prepass2(
    const int* __restrict__ tr,
    short* __restrict__ redL, short* __restrict__ redR,
    short* __restrict__ uL, short* __restrict__ uR,
    short* __restrict__ cL, short* __restrict__ cR,
    int* __restrict__ nred, int* __restrict__ encRef,
    int* __restrict__ gIter, int* __restrict__ anyLR){
  __shared__ int trs[STEPS_];
  int b = blockIdx.x, lane = threadIdx.x;
  for (int i = lane; i < STEPS_; i += 64) trs[i] = tr[b*STEPS_ + i];
  __syncthreads();
  if (lane != 0) return;
  short stk[T_ + 2];
  stk[0] = (short)REF_ZERO; stk[1] = (short)REF_ZERO;
  int ptr = 2, bptr = 0, k = 0;
  int g = (b & 1) ? 4 + ((b >> 1) >> 4) : ((b >> 1) >> 4);
  for (int t = 0; t < STEPS_; t++){
    int tt = trs[t];
    int rl = -1, rr = -1;
    if (tt == 0){                      // SHIFT
      int j = bptr; if (j > T_-1) j = T_-1;
      int wi = ptr; if (wi < 0) wi = 0; if (wi > T_+1) wi = T_+1;
      stk[wi] = (short)j;
      ptr++; bptr++;
    } else if (tt == 1){               // REDUCE
      int i1 = ptr-1; if (i1 < 0) i1 = 0; if (i1 > T_+1) i1 = T_+1;
      int i2 = ptr-2; if (i2 < 0) i2 = 0; if (i2 > T_+1) i2 = T_+1;
      rr = stk[i1]; rl = stk[i2];
      short sL = (rl >= 0 && rl < REF_COMP) ? (short)rl : (short)-1;   // static buf
      short sR = (rr >= 0 && rr < REF_COMP) ? (short)rr : (short)-1;
      short dL = (rl >= REF_COMP && rl < REF_ZERO) ? (short)(rl - REF_COMP) : (short)-1; // dyn comp
      short dR = (rr >= REF_COMP && rr < REF_ZERO) ? (short)(rr - REF_COMP) : (short)-1;
      uL[b*128 + k] = sL; uR[b*128 + k] = sR;
      cL[b*128 + k] = dL; cR[b*128 + k] = dR;
      int bits = (dL >= 0 ? 1 : 0) | (dR >= 0 ? 2 : 0);
      if (bits) atomicOr(anyLR + g*128 + k, bits);
      int wi = ptr-2; if (wi < 0) wi = 0; if (wi > T_+1) wi = T_+1;
      stk[wi] = (short)(REF_COMP + k);
      k++; ptr--;
    }                                  // SKIP: no change
    redL[b*STEPS_ + t] = (short)rl;
    redR[b*STEPS_ + t] = (short)rr;
  }
  for (int kk = k; kk < 128; kk++){
    uL[b*128+kk] = -1; uR[b*128+kk] = -1; cL[b*128+kk] = -1; cR[b*128+kk] = -1;
  }
  int ei = ptr-1; if (ei < 0) ei = 0; if (ei > T_+1) ei = T_+1;
  encRef[b] = stk[ei];
  nred[b] = k;
  atomicMax(gIter + g, k);
}

// ---------------- W prep: fp32 [1024][512] -> bf16 MFMA-B-fragment-linear ----
__global__ void k_wprep(const float* __restrict__ W, unsigned short* __restrict__ Wo){
  int t = blockIdx.x*256 + threadIdx.x;           // t < 524288
  int e  = t & 7;
  int l  = (t >> 3) & 63;
  int kt = (t >> 9) & 31;
  int nt = (t >> 14);
  int krow = kt*32 + (l >> 4)*8 + e;
  int ncol = nt*16 + (l & 15);
  Wo[t] = rne_bf16(W[krow*512 + ncol]);
}

// ---------------- U GEMM: U[(b,k)][col] = W_L*leftStatic + W_R*rightStatic + b
__global__ __launch_bounds__(256) void k_ugemm(
    const float* __restrict__ bufs, const float* __restrict__ bias,
    const unsigned short* __restrict__ Wo,
    const short* __restrict__ uL, const short* __restrict__ uR,
    const float* __restrict__ zeroF, unsigned short* __restrict__ U){
  int mt = blockIdx.x & 255, ntB = blockIdx.x >> 8;
  int w = threadIdx.x >> 6, lane = threadIdx.x & 63;
  int rbase = mt*64 + w*16;
  int arow = rbase + (lane & 15);
  int b = arow >> 7;
  int refL = (int)uL[arow], refR = (int)uR[arow];
  const float* pL = (refL >= 0) ? (bufs + ((size_t)b*T_ + refL)*D_) : zeroF;
  const float* pR = (refR >= 0) ? (bufs + ((size_t)b*T_ + refR)*D_) : zeroF;
  int eoff = (lane >> 4) * 8;
  float4v acc[8];
  #pragma unroll
  for (int nt = 0; nt < 8; ++nt) acc[nt] = (float4v){0.f,0.f,0.f,0.f};
  for (int kt = 0; kt < 32; ++kt){
    const float* src = (kt < 16) ? pL : pR;
    int off = (kt & 15)*32 + eoff;
    float4v f0 = *reinterpret_cast<const float4v*>(src + off);
    float4v f1 = *reinterpret_cast<const float4v*>(src + off + 4);
    short8 a;
    a[0]=(short)rne_bf16(f0[0]); a[1]=(short)rne_bf16(f0[1]);
    a[2]=(short)rne_bf16(f0[2]); a[3]=(short)rne_bf16(f0[3]);
    a[4]=(short)rne_bf16(f1[0]); a[5]=(short)rne_bf16(f1[1]);
    a[6]=(short)rne_bf16(f1[2]); a[7]=(short)rne_bf16(f1[3]);
    #pragma unroll
    for (int nt = 0; nt < 8; ++nt){
      const short8* bp = reinterpret_cast<const short8*>(Wo)
                         + (((size_t)(ntB*8 + nt)*32 + kt)*64 + lane);
      acc[nt] = __builtin_amdgcn_mfma_f32_16x16x32_bf16(a, *bp, acc[nt], 0, 0, 0);
    }
  }
  #pragma unroll
  for (int nt = 0; nt < 8; ++nt){
    int col = ntB*128 + nt*16 + (lane & 15);
    float bc = bias[col];
    #pragma unroll
    for (int j = 0; j < 4; ++j){
      int orow = rbase + (lane >> 4)*4 + j;
      U[(size_t)orow*512 + col] = rne_bf16(acc[nt][j] + bc);
    }
  }
}

// ---------------- chain: 8 groups x 2 WGs (256-col half), W_L truly in VGPRs -
// Rule-#20 fix vs r10: W fragments in FOUR compile-time-indexed arrays
// (own/partner K-half x 2 ntiles); runtime h only in load ADDRESSES.
// Phase1: own K-half from LDS c-buffer (no sync). Phase2: partner 8KB half
// after ONE flag poll + one sc0sc1 vector load.
__global__ __launch_bounds__(512, 2) void k_chain9(
    const unsigned short* __restrict__ Wo, const unsigned short* __restrict__ U,
    const short* __restrict__ cL, const short* __restrict__ cR,
    const int* __restrict__ nred, const int* __restrict__ gIter,
    const int* __restrict__ anyLR, const unsigned short* __restrict__ zeroPg,
    unsigned short* __restrict__ CompBf, int* __restrict__ flags){
  __shared__ unsigned short cbuf[2][4096];        // [k-parity][16 rows x 256 cols]
  const int tid = threadIdx.x, lane = tid & 63, w = tid >> 6;
  const int g = blockIdx.x >> 1, h = blockIdx.x & 1;
  const int colLane = lane & 15, rq = lane >> 4;

  // W_L B-fragments in VGPRs, compile-time indices only (rule #20)
  const short8* WoF = reinterpret_cast<const short8*>(Wo);
  const int nt0 = h*16 + w*2, nt1 = nt0 + 1;
  short8 WOa[8], WOb[8], WPa[8], WPb[8];
  #pragma unroll
  for (int i = 0; i < 8; ++i){
    WOa[i] = WoF[((size_t)nt0*32 + h*8 + i)*64 + lane];       // own half, ntile 0
    WOb[i] = WoF[((size_t)nt1*32 + h*8 + i)*64 + lane];       // own half, ntile 1
    WPa[i] = WoF[((size_t)nt0*32 + (h^1)*8 + i)*64 + lane];   // partner half, nt 0
    WPb[i] = WoF[((size_t)nt1*32 + (h^1)*8 + i)*64 + lane];   // partner half, nt 1
  }

  const int myb = rowB(g*16 + colLane);
  const int myNred = nred[myb];
  const int iters = gIter[g];
  int bS[4];
  #pragma unroll
  for (int j = 0; j < 4; ++j) bS[j] = rowB(g*16 + rq*4 + j);
  const int col0 = nt0*16 + colLane;              // global col of t=0
  size_t Ub[4];
  #pragma unroll
  for (int j = 0; j < 4; ++j) Ub[j] = (size_t)bS[j]*65536 + col0;

  int* pflag = flags + ((g*2 + (h^1)) << 4);      // partner's flag
  int* mflag = flags + ((g*2 + h) << 4);          // mine

  for (int k = 0; k < iters; ++k){
    const int afl = anyLR[g*128 + k];
    // U prefetch — consumed only at tanh, so HBM latency hides under phases
    unsigned short uv0[4], uv1[4];
    #pragma unroll
    for (int j = 0; j < 4; ++j){
      uv0[j] = U[Ub[j] + (size_t)k*512];
      uv1[j] = U[Ub[j] + (size_t)k*512 + 16];
    }
    float4v accA0 = {0.f,0.f,0.f,0.f}, accA1 = {0.f,0.f,0.f,0.f};
    float4v accB0 = {0.f,0.f,0.f,0.f}, accB1 = {0.f,0.f,0.f,0.f};

    if (afl != 0){
      int rl = (k < myNred) ? (int)cL[myb*128 + k] : -1;
      if (afl & 1){
        // ---- phase 1: own K-half (no cross-WG dependency) ----
        bool ownLds = (k > 0) && __all((rl == k-1) || (rl < 0));
        short8 aO[8];
        if (ownLds){
          const char* cb = (const char*)cbuf[(k-1) & 1];
          int base = colLane*512 + rq*16;
          #pragma unroll
          for (int i = 0; i < 8; ++i){
            int ad = (base + i*64) ^ ((colLane & 7) << 4);
            aO[i] = *reinterpret_cast<const short8*>(cb + ad);
          }
        } else {
          const char* p = (rl >= 0)
            ? (const char*)(CompBf + ((size_t)myb*128 + rl)*512 + h*256)
            : (const char*)zeroPg;
          load_c8(p + rq*16, aO);
        }
        if (rl < 0){
          #pragma unroll
          for (int i = 0; i < 8; ++i) aO[i] = (short8)0;
        }
        #pragma unroll
        for (int i = 0; i < 8; ++i){
          accA0 = __builtin_amdgcn_mfma_f32_16x16x32_bf16(aO[i], WOa[i], accA0, 0, 0, 0);
          accA1 = __builtin_amdgcn_mfma_f32_16x16x32_bf16(aO[i], WOb[i], accA1, 0, 0, 0);
        }
      }
      // ---- sync: partner's step k-1 must be complete ----
      if (k > 0){
        int guard = 0;
        for (;;){
          int fv = __hip_atomic_load(pflag, __ATOMIC_RELAXED, __HIP_MEMORY_SCOPE_AGENT);
          if (fv >= k) break;
          __builtin_amdgcn_s_sleep(1);
          if (++guard > (1 << 26)) break;         // safety: never hang
        }
        asm volatile("" ::: "memory");            // compiler ordering only
      }
      if (afl & 1){
        // ---- phase 2: partner K-half via LLC ----
        short8 aP[8];
        const char* p = (rl >= 0)
          ? (const char*)(CompBf + ((size_t)myb*128 + rl)*512 + (h^1)*256)
          : (const char*)zeroPg;
        load_c8(p + rq*16, aP);
        if (rl < 0){
          #pragma unroll
          for (int i = 0; i < 8; ++i) aP[i] = (short8)0;
        }
        #pragma unroll
        for (int i = 0; i < 8; ++i){
          accB0 = __builtin_amdgcn_mfma_f32_16x16x32_bf16(aP[i], WPa[i], accB0, 0, 0, 0);
          accB1 = __builtin_amdgcn_mfma_f32_16x16x32_bf16(aP[i], WPb[i], accB1, 0, 0, 0);
        }
      }
      if (afl & 2){
        // ---- general fallback: dynamic right; W_R frags from global Wo ----
        int rr = (k < myNred) ? (int)cR[myb*128 + k] : -1;
        const char* p = (rr >= 0)
          ? (const char*)(CompBf + ((size_t)myb*128 + rr)*512)
          : (const char*)zeroPg;
        #pragma unroll
        for (int half = 0; half < 2; ++half){
          short8 aR[8];
          load_c8(p + half*512 + rq*16, aR);
          if (rr < 0){
            #pragma unroll
            for (int i = 0; i < 8; ++i) aR[i] = (short8)0;
          }
          #pragma unroll
          for (int i = 0; i < 8; ++i){
            const short8* bp0 = WoF + (((size_t)nt0*32 + 16 + half*8 + i)*64 + lane);
            const short8* bp1 = WoF + (((size_t)nt1*32 + 16 + half*8 + i)*64 + lane);
            accB0 = __builtin_amdgcn_mfma_f32_16x16x32_bf16(aR[i], *bp0, accB0, 0, 0, 0);
            accB1 = __builtin_amdgcn_mfma_f32_16x16x32_bf16(aR[i], *bp1, accB1, 0, 0, 0);
          }
        }
      }
    }
    // ---- finish: tanh(U + acc), scatter to CompBf (sc0sc1) + own LDS half ----
    char* cw = (char*)cbuf[k & 1];
    #pragma unroll
    for (int j = 0; j < 4; ++j){
      float v0 = fast_tanh(accA0[j] + accB0[j] + bf2f(uv0[j]));
      float v1 = fast_tanh(accA1[j] + accB1[j] + bf2f(uv1[j]));
      unsigned us0 = (unsigned)rne_bf16(v0);
      unsigned us1 = (unsigned)rne_bf16(v1);
      size_t rb = ((size_t)bS[j]*128 + k)*512;
      cstore_cc(CompBf + rb + col0, us0);
      cstore_cc(CompBf + rb + col0 + 16, us1);
      int rloc = rq*4 + j;
      int c0 = (w*2)*16 + colLane;                // local col of t=0
      int ad0 = (rloc*512 + c0*2) ^ ((rloc & 7) << 4);
      int ad1 = (rloc*512 + (c0 + 16)*2) ^ ((rloc & 7) << 4);
      *reinterpret_cast<unsigned short*>(cw + ad0) = (unsigned short)us0;
      *reinterpret_cast<unsigned short*>(cw + ad1) = (unsigned short)us1;
    }
    asm volatile("s_waitcnt vmcnt(0)" ::: "memory");  // my c-half at LLC
    __syncthreads();                                   // all waves drained + LDS done
    if (tid == 0)
      __hip_atomic_store(mflag, k + 1, __ATOMIC_RELAXED, __HIP_MEMORY_SCOPE_AGENT);
  }
}

// ---------------- output writer: pure copy/scatter, memory-bound ------------
__global__ __launch_bounds__(256) void k_out(
    const float* __restrict__ bufs, const unsigned short* __restrict__ CompBf,
    const short* __restrict__ redL, const short* __restrict__ redR,
    const int* __restrict__ encRef, float* __restrict__ out)
{
  int r = blockIdx.x*2 + (threadIdx.x >> 7);      // 65536 output rows of 512 f32
  int q = threadIdx.x & 127;                      // float4 index within row
  int ref, b;
  float* dst;
  if (r < B_){                                    // enc block
    b = r; ref = encRef[r];
    dst = out + (size_t)r*D_;
  } else {                                        // attended block
    int z = r - B_;
    b = z / 511; int s = z - b*511;
    dst = out + (size_t)B_*D_ + (size_t)z*D_;
    if (s == 510) ref = encRef[b];
    else { int t = s >> 1; ref = (s & 1) ? (int)redR[b*STEPS_ + t] : (int)redL[b*STEPS_ + t]; }
  }
  float4v v = {0.f, 0.f, 0.f, 0.f};
  if (ref >= 0 && ref < REF_COMP){
    v = reinterpret_cast<const float4v*>(bufs + ((size_t)b*T_ + ref)*D_)[q];
  } else if (ref >= REF_COMP && ref < REF_ZERO){
    ushort4v u = reinterpret_cast<const ushort4v*>(CompBf + ((size_t)b*128 + (ref - REF_COMP))*D_)[q];
    v[0] = bf2f(u[0]); v[1] = bf2f(u[1]); v[2] = bf2f(u[2]); v[3] = bf2f(u[3]);
  }
  reinterpret_cast<float4v*>(dst)[q] = v;
}

// ---------------- launch ----------------------------------------------------
extern "C" void kernel_launch(void* const* d_in, const int* in_sizes, int n_in,
                              void* d_out, int out_size, void* d_ws, size_t ws_size,
                              hipStream_t stream){
  const float* bufs = (const float*)d_in[0];
  const float* W    = (const float*)d_in[1];
  const float* bias = (const float*)d_in[2];
  const int*   tr   = (const int*)d_in[3];
  float* out = (float*)d_out;
  char* ws = (char*)d_ws;

  unsigned short* Wo     = (unsigned short*)(ws);               //  1,048,576
  unsigned short* CompBf = (unsigned short*)(ws + 1048576);     // 16,777,216
  unsigned short* U      = (unsigned short*)(ws + 17825792);    // 16,777,216
  short* redL   = (short*)(ws + 34603008);                      //     65,536
  short* redR   = (short*)(ws + 34668544);                      //     65,536
  short* uL     = (short*)(ws + 34734080);                      //     32,768
  short* uR     = (short*)(ws + 34766848);                      //     32,768
  short* cL     = (short*)(ws + 34799616);                      //     32,768
  short* cR     = (short*)(ws + 34832384);                      //     32,768
  int* nred     = (int*)(ws + 34865152);                        //        512
  int* encRef   = (int*)(ws + 34865664);                        //        512
  int* gIter    = (int*)(ws + 34866176);                        //        256
  int* flags    = (int*)(ws + 34866432);                        //      8,192
  int* anyLR    = (int*)(ws + 34874624);                        //      4,096
  unsigned short* zeroPg = (unsigned short*)(ws + 34878720);    //      2,048

  k_zero<<<1, 256, 0, stream>>>(flags, anyLR, gIter, zeroPg);
  k_prepass2<<<128, 64, 0, stream>>>(tr, redL, redR, uL, uR, cL, cR, nred, encRef, gIter, anyLR);
  k_wprep<<<2048, 256, 0, stream>>>(W, Wo);
  k_ugemm<<<1024, 256, 0, stream>>>(bufs, bias, Wo, uL, uR, (const float*)zeroPg, U);
  k_chain9<<<16, 512, 0, stream>>>(Wo, U, cL, cR, nred, gIter, anyLR, zeroPg, CompBf, flags);
  k_out<<<32768, 256, 0, stream>>>(bufs, CompBf, redL, redR, encRef, out);
}

// Round 14
// 651.512 us; speedup vs baseline: 2.5106x; 1.4718x over previous
//
#include <hip/hip_runtime.h>
#include <hip/hip_bf16.h>
#include <math.h>

#define B_ 128
#define T_ 128
#define D_ 512
#define STEPS_ 255

#define REF_COMP 4096
#define REF_ZERO 8192

using short8   = __attribute__((ext_vector_type(8))) short;
using ushort8  = __attribute__((ext_vector_type(8))) unsigned short;
using ushort4v = __attribute__((ext_vector_type(4))) unsigned short;
using float4v  = __attribute__((ext_vector_type(4))) float;

__device__ __forceinline__ unsigned short rne_bf16(float f){
  union { float f; unsigned u; } v; v.f = f;
  unsigned u = v.u;
  u += 0x7FFFu + ((u >> 16) & 1u);
  return (unsigned short)(u >> 16);
}
__device__ __forceinline__ float bf2f(unsigned short u){
  union { unsigned u; float f; } x; x.u = ((unsigned)u) << 16; return x.f;
}
__device__ __forceinline__ float fast_tanh(float x){
  float xc = fminf(9.0f, fmaxf(-9.0f, x));
  float e  = __expf(2.0f * xc);
  return (e - 1.0f) * __builtin_amdgcn_rcpf(e + 1.0f);
}
// parity grouping: group-slot j -> batch row (evens first, then odds)
__device__ __forceinline__ int rowB(int j){ return (j < 64) ? (2*j) : (2*(j-64)+1); }

// 16 x 16B coherent (LLC) loads of one c-vector's A-fragments, 1 round-trip.
__device__ __forceinline__ void load_c_cc(const char* p, short8* a){
  asm volatile(
    "global_load_dwordx4 %0, %16, off sc0 sc1\n\t"
    "global_load_dwordx4 %1, %16, off offset:64 sc0 sc1\n\t"
    "global_load_dwordx4 %2, %16, off offset:128 sc0 sc1\n\t"
    "global_load_dwordx4 %3, %16, off offset:192 sc0 sc1\n\t"
    "global_load_dwordx4 %4, %16, off offset:256 sc0 sc1\n\t"
    "global_load_dwordx4 %5, %16, off offset:320 sc0 sc1\n\t"
    "global_load_dwordx4 %6, %16, off offset:384 sc0 sc1\n\t"
    "global_load_dwordx4 %7, %16, off offset:448 sc0 sc1\n\t"
    "global_load_dwordx4 %8, %16, off offset:512 sc0 sc1\n\t"
    "global_load_dwordx4 %9, %16, off offset:576 sc0 sc1\n\t"
    "global_load_dwordx4 %10, %16, off offset:640 sc0 sc1\n\t"
    "global_load_dwordx4 %11, %16, off offset:704 sc0 sc1\n\t"
    "global_load_dwordx4 %12, %16, off offset:768 sc0 sc1\n\t"
    "global_load_dwordx4 %13, %16, off offset:832 sc0 sc1\n\t"
    "global_load_dwordx4 %14, %16, off offset:896 sc0 sc1\n\t"
    "global_load_dwordx4 %15, %16, off offset:960 sc0 sc1\n\t"
    "s_waitcnt vmcnt(0)"
    : "=&v"(a[0]), "=&v"(a[1]), "=&v"(a[2]), "=&v"(a[3]),
      "=&v"(a[4]), "=&v"(a[5]), "=&v"(a[6]), "=&v"(a[7]),
      "=&v"(a[8]), "=&v"(a[9]), "=&v"(a[10]), "=&v"(a[11]),
      "=&v"(a[12]), "=&v"(a[13]), "=&v"(a[14]), "=&v"(a[15])
    : "v"(p)
    : "memory");
}

__device__ __forceinline__ void cstore_cc(unsigned short* p, unsigned v){
  asm volatile("global_store_short %0, %1, off sc0 sc1" :: "v"(p), "v"(v) : "memory");
}

// ---------------- zero init: flags / bitmaps / zero page ---------------------
__global__ void k_zero(int* __restrict__ flags, int* __restrict__ anyLR,
                       int* __restrict__ gIter, unsigned short* __restrict__ zeroPg){
  int t = threadIdx.x;
  for (int i = t; i < 2048; i += 256) flags[i] = 0;
  for (int i = t; i < 1024; i += 256) anyLR[i] = 0;
  if (t < 16) gIter[t] = 0;
  for (int i = t; i < 1024; i += 256) zeroPg[i] = 0;
}

// ---------------- pre-pass: symbolic stack simulation (1 block / row) --------
// ref encoding: 0..127 = BUF idx; 4096+k = COMP k; 8192 = initial zero; -1 = none
__global__ __launch_bounds__(64) void k_prepass2(
    const int* __restrict__ tr,
    short* __restrict__ redL, short* __restrict__ redR,
    short* __restrict__ uL, short* __restrict__ uR,
    short* __restrict__ cL, short* __restrict__ cR,
    int* __restrict__ nred, int* __restrict__ encRef,
    int* __restrict__ gIter, int* __restrict__ anyLR){
  __shared__ int trs[STEPS_];
  int b = blockIdx.x, lane = threadIdx.x;
  for (int i = lane; i < STEPS_; i += 64) trs[i] = tr[b*STEPS_ + i];
  __syncthreads();
  if (lane != 0) return;
  short stk[T_ + 2];
  stk[0] = (short)REF_ZERO; stk[1] = (short)REF_ZERO;
  int ptr = 2, bptr = 0, k = 0;
  int g = (b & 1) ? 4 + ((b >> 1) >> 4) : ((b >> 1) >> 4);
  for (int t = 0; t < STEPS_; t++){
    int tt = trs[t];
    int rl = -1, rr = -1;
    if (tt == 0){                      // SHIFT
      int j = bptr; if (j > T_-1) j = T_-1;
      int wi = ptr; if (wi < 0) wi = 0; if (wi > T_+1) wi = T_+1;
      stk[wi] = (short)j;
      ptr++; bptr++;
    } else if (tt == 1){               // REDUCE
      int i1 = ptr-1; if (i1 < 0) i1 = 0; if (i1 > T_+1) i1 = T_+1;
      int i2 = ptr-2; if (i2 < 0) i2 = 0; if (i2 > T_+1) i2 = T_+1;
      rr = stk[i1]; rl = stk[i2];
      short sL = (rl >= 0 && rl < REF_COMP) ? (short)rl : (short)-1;   // static buf
      short sR = (rr >= 0 && rr < REF_COMP) ? (short)rr : (short)-1;
      short dL = (rl >= REF_COMP && rl < REF_ZERO) ? (short)(rl - REF_COMP) : (short)-1; // dyn comp
      short dR = (rr >= REF_COMP && rr < REF_ZERO) ? (short)(rr - REF_COMP) : (short)-1;
      uL[b*128 + k] = sL; uR[b*128 + k] = sR;
      cL[b*128 + k] = dL; cR[b*128 + k] = dR;
      int bits = (dL >= 0 ? 1 : 0) | (dR >= 0 ? 2 : 0);
      if (bits) atomicOr(anyLR + g*128 + k, bits);
      int wi = ptr-2; if (wi < 0) wi = 0; if (wi > T_+1) wi = T_+1;
      stk[wi] = (short)(REF_COMP + k);
      k++; ptr--;
    }                                  // SKIP: no change
    redL[b*STEPS_ + t] = (short)rl;
    redR[b*STEPS_ + t] = (short)rr;
  }
  for (int kk = k; kk < 128; kk++){
    uL[b*128+kk] = -1; uR[b*128+kk] = -1; cL[b*128+kk] = -1; cR[b*128+kk] = -1;
  }
  int ei = ptr-1; if (ei < 0) ei = 0; if (ei > T_+1) ei = T_+1;
  encRef[b] = stk[ei];
  nred[b] = k;
  atomicMax(gIter + g, k);
}

// ---------------- W prep: fp32 [1024][512] -> bf16 MFMA-B-fragment-linear ----
__global__ void k_wprep(const float* __restrict__ W, unsigned short* __restrict__ Wo){
  int t = blockIdx.x*256 + threadIdx.x;           // t < 524288
  int e  = t & 7;
  int l  = (t >> 3) & 63;
  int kt = (t >> 9) & 31;
  int nt = (t >> 14);
  int krow = kt*32 + (l >> 4)*8 + e;
  int ncol = nt*16 + (l & 15);
  Wo[t] = rne_bf16(W[krow*512 + ncol]);
}

// ---------------- U GEMM: U[(b,k)][col] = W_L*leftStatic + W_R*rightStatic + b
__global__ __launch_bounds__(256) void k_ugemm(
    const float* __restrict__ bufs, const float* __restrict__ bias,
    const unsigned short* __restrict__ Wo,
    const short* __restrict__ uL, const short* __restrict__ uR,
    const float* __restrict__ zeroF, unsigned short* __restrict__ U){
  int mt = blockIdx.x & 255, ntB = blockIdx.x >> 8;
  int w = threadIdx.x >> 6, lane = threadIdx.x & 63;
  int rbase = mt*64 + w*16;
  int arow = rbase + (lane & 15);
  int b = arow >> 7;
  int refL = (int)uL[arow], refR = (int)uR[arow];
  const float* pL = (refL >= 0) ? (bufs + ((size_t)b*T_ + refL)*D_) : zeroF;
  const float* pR = (refR >= 0) ? (bufs + ((size_t)b*T_ + refR)*D_) : zeroF;
  int eoff = (lane >> 4) * 8;
  float4v acc[8];
  #pragma unroll
  for (int nt = 0; nt < 8; ++nt) acc[nt] = (float4v){0.f,0.f,0.f,0.f};
  for (int kt = 0; kt < 32; ++kt){
    const float* src = (kt < 16) ? pL : pR;
    int off = (kt & 15)*32 + eoff;
    float4v f0 = *reinterpret_cast<const float4v*>(src + off);
    float4v f1 = *reinterpret_cast<const float4v*>(src + off + 4);
    short8 a;
    a[0]=(short)rne_bf16(f0[0]); a[1]=(short)rne_bf16(f0[1]);
    a[2]=(short)rne_bf16(f0[2]); a[3]=(short)rne_bf16(f0[3]);
    a[4]=(short)rne_bf16(f1[0]); a[5]=(short)rne_bf16(f1[1]);
    a[6]=(short)rne_bf16(f1[2]); a[7]=(short)rne_bf16(f1[3]);
    #pragma unroll
    for (int nt = 0; nt < 8; ++nt){
      const short8* bp = reinterpret_cast<const short8*>(Wo)
                         + (((size_t)(ntB*8 + nt)*32 + kt)*64 + lane);
      acc[nt] = __builtin_amdgcn_mfma_f32_16x16x32_bf16(a, *bp, acc[nt], 0, 0, 0);
    }
  }
  #pragma unroll
  for (int nt = 0; nt < 8; ++nt){
    int col = ntB*128 + nt*16 + (lane & 15);
    float bc = bias[col];
    #pragma unroll
    for (int j = 0; j < 4; ++j){
      int orow = rbase + (lane >> 4)*4 + j;
      U[(size_t)orow*512 + col] = rne_bf16(acc[nt][j] + bc);
    }
  }
}

// ---------------- chain: 8 groups x 8 single-wave WGs (64-col slice each) ----
// W_L slice (4 ntiles x 16 kt, K=512) fully VGPR-resident: 256 VGPRs in four
// compile-time-indexed arrays (runtime wv only in load ADDRESSES, rule #20).
// No LDS, no intra-WG barrier. Sync = r7's proven per-wave-flag + sc0sc1
// vector exchange, but 8 participants instead of 16.
__global__ __launch_bounds__(64, 1) void k_chain10(
    const unsigned short* __restrict__ Wo, const unsigned short* __restrict__ U,
    const short* __restrict__ cL, const short* __restrict__ cR,
    const int* __restrict__ nred, const int* __restrict__ gIter,
    const int* __restrict__ anyLR, const unsigned short* __restrict__ zeroPg,
    unsigned short* __restrict__ CompBf, int* __restrict__ flags){
  const int lane = threadIdx.x;
  const int g = blockIdx.x >> 3, wv = blockIdx.x & 7;
  const int colLane = lane & 15, rq = lane >> 4;
  const int aoffB = rq * 16;                      // byte offset within 64B k-segment

  // W_L B-fragments -> VGPRs (compile-time indices only)
  const short8* WoF = reinterpret_cast<const short8*>(Wo);
  const int nt0 = wv*4;
  short8 W0[16], W1[16], W2[16], W3[16];
  #pragma unroll
  for (int i = 0; i < 16; ++i){
    W0[i] = WoF[((size_t)(nt0+0)*32 + i)*64 + lane];
    W1[i] = WoF[((size_t)(nt0+1)*32 + i)*64 + lane];
    W2[i] = WoF[((size_t)(nt0+2)*32 + i)*64 + lane];
    W3[i] = WoF[((size_t)(nt0+3)*32 + i)*64 + lane];
  }

  const int myb = rowB(g*16 + colLane);
  const int myNred = nred[myb];
  const int iters = gIter[g];
  int bS[4], nredS[4];
  #pragma unroll
  for (int j = 0; j < 4; ++j){
    bS[j] = rowB(g*16 + rq*4 + j);
    nredS[j] = nred[bS[j]];
  }
  const int col0 = nt0*16 + colLane;              // global col of ntile 0
  size_t Ub[4];
  #pragma unroll
  for (int j = 0; j < 4; ++j) Ub[j] = (size_t)bS[j]*65536 + col0;

  int* mflag = flags + ((g*8 + wv) << 4);

  for (int k = 0; k < iters; ++k){
    const int afl = anyLR[g*128 + k];
    // U prefetch (plain cached loads; consumed only at tanh)
    unsigned short uv0[4], uv1[4], uv2[4], uv3[4];
    #pragma unroll
    for (int j = 0; j < 4; ++j){
      size_t ub = Ub[j] + (size_t)k*512;
      uv0[j] = U[ub]; uv1[j] = U[ub + 16]; uv2[j] = U[ub + 32]; uv3[j] = U[ub + 48];
    }
    float4v a0 = {0.f,0.f,0.f,0.f}, a1 = {0.f,0.f,0.f,0.f};
    float4v a2 = {0.f,0.f,0.f,0.f}, a3 = {0.f,0.f,0.f,0.f};

    if (afl != 0){
      int rl = (k < myNred) ? (int)cL[myb*128 + k] : -1;
      if (k > 0){
        int guard = 0;
        for (;;){
          int fv = (lane < 8)
            ? __hip_atomic_load(flags + ((g*8 + lane) << 4), __ATOMIC_RELAXED, __HIP_MEMORY_SCOPE_AGENT)
            : 0x7FFFFFFF;
          if (__all(fv >= k)) break;
          __builtin_amdgcn_s_sleep(1);
          if (++guard > (1 << 26)) break;         // safety: never hang
        }
        asm volatile("" ::: "memory");            // compiler ordering only
      }
      if (afl & 1){                               // dynamic left (the chain dep)
        const char* p = (rl >= 0)
          ? (const char*)(CompBf + ((size_t)myb*128 + rl)*512)
          : (const char*)zeroPg;
        short8 aL[16];
        load_c_cc(p + aoffB, aL);
        if (rl < 0){
          #pragma unroll
          for (int i = 0; i < 16; ++i) aL[i] = (short8)0;
        }
        #pragma unroll
        for (int i = 0; i < 16; ++i){
          a0 = __builtin_amdgcn_mfma_f32_16x16x32_bf16(aL[i], W0[i], a0, 0, 0, 0);
          a1 = __builtin_amdgcn_mfma_f32_16x16x32_bf16(aL[i], W1[i], a1, 0, 0, 0);
          a2 = __builtin_amdgcn_mfma_f32_16x16x32_bf16(aL[i], W2[i], a2, 0, 0, 0);
          a3 = __builtin_amdgcn_mfma_f32_16x16x32_bf16(aL[i], W3[i], a3, 0, 0, 0);
        }
      }
      if (afl & 2){                               // dynamic right (general fallback;
        int rr = (k < myNred) ? (int)cR[myb*128 + k] : -1;  // W_R frags from global)
        const char* p = (rr >= 0)
          ? (const char*)(CompBf + ((size_t)myb*128 + rr)*512)
          : (const char*)zeroPg;
        short8 aR[16];
        load_c_cc(p + aoffB, aR);
        if (rr < 0){
          #pragma unroll
          for (int i = 0; i < 16; ++i) aR[i] = (short8)0;
        }
        #pragma unroll
        for (int i = 0; i < 16; ++i){
          a0 = __builtin_amdgcn_mfma_f32_16x16x32_bf16(aR[i],
                 WoF[((size_t)(nt0+0)*32 + 16 + i)*64 + lane], a0, 0, 0, 0);
          a1 = __builtin_amdgcn_mfma_f32_16x16x32_bf16(aR[i],
                 WoF[((size_t)(nt0+1)*32 + 16 + i)*64 + lane], a1, 0, 0, 0);
          a2 = __builtin_amdgcn_mfma_f32_16x16x32_bf16(aR[i],
                 WoF[((size_t)(nt0+2)*32 + 16 + i)*64 + lane], a2, 0, 0, 0);
          a3 = __builtin_amdgcn_mfma_f32_16x16x32_bf16(aR[i],
                 WoF[((size_t)(nt0+3)*32 + 16 + i)*64 + lane], a3, 0, 0, 0);
        }
      }
    }
    // tanh(acc + U) + coherent scatter of this wave's 64-col slice
    #pragma unroll
    for (int j = 0; j < 4; ++j){
      if (k < nredS[j]){
        size_t rb = ((size_t)bS[j]*128 + k)*512 + col0;
        cstore_cc(CompBf + rb,      (unsigned)rne_bf16(fast_tanh(a0[j] + bf2f(uv0[j]))));
        cstore_cc(CompBf + rb + 16, (unsigned)rne_bf16(fast_tanh(a1[j] + bf2f(uv1[j]))));
        cstore_cc(CompBf + rb + 32, (unsigned)rne_bf16(fast_tanh(a2[j] + bf2f(uv2[j]))));
        cstore_cc(CompBf + rb + 48, (unsigned)rne_bf16(fast_tanh(a3[j] + bf2f(uv3[j]))));
      }
    }
    asm volatile("s_waitcnt vmcnt(0)" ::: "memory");  // c at LLC before flag
    if (lane == 0)
      __hip_atomic_store(mflag, k + 1, __ATOMIC_RELAXED, __HIP_MEMORY_SCOPE_AGENT);
  }
}

// ---------------- output writer: pure copy/scatter, memory-bound ------------
__global__ __launch_bounds__(256) void k_out(
    const float* __restrict__ bufs, const unsigned short* __restrict__ CompBf,
    const short* __restrict__ redL, const short* __restrict__ redR,
    const int* __restrict__ encRef, float* __restrict__ out)
{
  int r = blockIdx.x*2 + (threadIdx.x >> 7);      // 65536 output rows of 512 f32
  int q = threadIdx.x & 127;                      // float4 index within row
  int ref, b;
  float* dst;
  if (r < B_){                                    // enc block
    b = r; ref = encRef[r];
    dst = out + (size_t)r*D_;
  } else {                                        // attended block
    int z = r - B_;
    b = z / 511; int s = z - b*511;
    dst = out + (size_t)B_*D_ + (size_t)z*D_;
    if (s == 510) ref = encRef[b];
    else { int t = s >> 1; ref = (s & 1) ? (int)redR[b*STEPS_ + t] : (int)redL[b*STEPS_ + t]; }
  }
  float4v v = {0.f, 0.f, 0.f, 0.f};
  if (ref >= 0 && ref < REF_COMP){
    v = reinterpret_cast<const float4v*>(bufs + ((size_t)b*T_ + ref)*D_)[q];
  } else if (ref >= REF_COMP && ref < REF_ZERO){
    ushort4v u = reinterpret_cast<const ushort4v*>(CompBf + ((size_t)b*128 + (ref - REF_COMP))*D_)[q];
    v[0] = bf2f(u[0]); v[1] = bf2f(u[1]); v[2] = bf2f(u[2]); v[3] = bf2f(u[3]);
  }
  reinterpret_cast<float4v*>(dst)[q] = v;
}

// ---------------- launch ----------------------------------------------------
extern "C" void kernel_launch(void* const* d_in, const int* in_sizes, int n_in,
                              void* d_out, int out_size, void* d_ws, size_t ws_size,
                              hipStream_t stream){
  const float* bufs = (const float*)d_in[0];
  const float* W    = (const float*)d_in[1];
  const float* bias = (const float*)d_in[2];
  const int*   tr   = (const int*)d_in[3];
  float* out = (float*)d_out;
  char* ws = (char*)d_ws;

  unsigned short* Wo     = (unsigned short*)(ws);               //  1,048,576
  unsigned short* CompBf = (unsigned short*)(ws + 1048576);     // 16,777,216
  unsigned short* U      = (unsigned short*)(ws + 17825792);    // 16,777,216
  short* redL   = (short*)(ws + 34603008);                      //     65,536
  short* redR   = (short*)(ws + 34668544);                      //     65,536
  short* uL     = (short*)(ws + 34734080);                      //     32,768
  short* uR     = (short*)(ws + 34766848);                      //     32,768
  short* cL     = (short*)(ws + 34799616);                      //     32,768
  short* cR     = (short*)(ws + 34832384);                      //     32,768
  int* nred     = (int*)(ws + 34865152);                        //        512
  int* encRef   = (int*)(ws + 34865664);                        //        512
  int* gIter    = (int*)(ws + 34866176);                        //        256
  int* flags    = (int*)(ws + 34866432);                        //      8,192
  int* anyLR    = (int*)(ws + 34874624);                        //      4,096
  unsigned short* zeroPg = (unsigned short*)(ws + 34878720);    //      2,048

  k_zero<<<1, 256, 0, stream>>>(flags, anyLR, gIter, zeroPg);
  k_prepass2<<<128, 64, 0, stream>>>(tr, redL, redR, uL, uR, cL, cR, nred, encRef, gIter, anyLR);
  k_wprep<<<2048, 256, 0, stream>>>(W, Wo);
  k_ugemm<<<1024, 256, 0, stream>>>(bufs, bias, Wo, uL, uR, (const float*)zeroPg, U);
  k_chain10<<<64, 64, 0, stream>>>(Wo, U, cL, cR, nred, gIter, anyLR, zeroPg, CompBf, flags);
  k_out<<<32768, 256, 0, stream>>>(bufs, CompBf, redL, redR, encRef, out);
}